// Round 3
// baseline (296.248 us; speedup 1.0000x reference)
//
#include <hip/hip_runtime.h>
#include <math.h>

#define NBINS 4
#define SLOTS 64   // atomic-spread slots per bin (fallback path only)

// Two-kernel structure (270.0us in round 2). Round-1 lesson: ANY agent-scope
// fence in the producer path emits per-block L2 writeback/invalidate ops ->
// 10x regression; the dispatch boundary IS the cheap device-scope release.
//
// Round 3 change: nontemporal loads -> plain cached loads. Round-1 counters
// showed FETCH_SIZE = 141.6 MB (one input's worth): ~half the data is
// L3-resident after the harness restore. NT's no-allocate hint forces the
// L3-hit half through a slow probe/bypass path (no L2 buffering); cached
// loads let it stream at cache BW. Restore fills already write through to
// HBM (WRITE_SIZE = 566 MB at 84% peak), so allocating clean read lines
// cannot amplify writeback.

#define CHUNK_F4 1024

typedef float fvec4 __attribute__((ext_vector_type(4)));

__global__ __launch_bounds__(256) void qrmse_bins(
    const fvec4* __restrict__ yp4, const fvec4* __restrict__ yt4,
    const float* __restrict__ yp, const float* __restrict__ yt,
    float* __restrict__ g_ss, unsigned int* __restrict__ g_cnt,   // slot path
    fvec4* __restrict__ g_bs, uint4* __restrict__ g_bc,           // partials path
    int n4, int n, int full_blocks, int use_partials)
{
    const float B1 = 1.7917594909667969f;   // log1p(5)  in f32
    const float B2 = 3.2580965518951416f;   // log1p(25)
    const float B3 = 3.9318256378173828f;   // log1p(50)
    const float B4 = 4.6151204109191895f;   // log1p(100)

    float ss0 = 0.f, ss1 = 0.f, ss2 = 0.f, ss3 = 0.f;
    unsigned int c0 = 0, c1 = 0, c2 = 0, c3 = 0;

#define ACC(PC, TC)                                          \
    {                                                        \
        float d  = (PC) - (TC);                              \
        float sq = d * d;                                    \
        float tv = (TC);                                     \
        bool b0 = (tv >= 0.f) & (tv < B1);                   \
        bool b1 = (tv >= B1)  & (tv < B2);                   \
        bool b2 = (tv >= B2)  & (tv < B3);                   \
        bool b3 = (tv >= B3)  & (tv < B4);                   \
        ss0 += b0 ? sq : 0.f;  c0 += b0;                     \
        ss1 += b1 ? sq : 0.f;  c1 += b1;                     \
        ss2 += b2 ? sq : 0.f;  c2 += b2;                     \
        ss3 += b3 ? sq : 0.f;  c3 += b3;                     \
    }
#define ACCF4(P, T)                                          \
    { ACC(P.x, T.x); ACC(P.y, T.y); ACC(P.z, T.z); ACC(P.w, T.w); }

    const int tid = threadIdx.x;
    const int b   = blockIdx.x;

    if (b < full_blocks) {
        // guard-free hot path: 8 independent cached 16B loads
        const fvec4* P = yp4 + (size_t)b * CHUNK_F4 + tid;
        const fvec4* T = yt4 + (size_t)b * CHUNK_F4 + tid;
        fvec4 p0 = P[0];
        fvec4 p1 = P[256];
        fvec4 p2 = P[512];
        fvec4 p3 = P[768];
        fvec4 t0 = T[0];
        fvec4 t1 = T[256];
        fvec4 t2 = T[512];
        fvec4 t3 = T[768];
        ACCF4(p0, t0); ACCF4(p1, t1); ACCF4(p2, t2); ACCF4(p3, t3);
    } else {
        // ragged last block (empty when n4 % CHUNK_F4 == 0)
        for (int i = full_blocks * CHUNK_F4 + tid; i < n4; i += 256) {
            fvec4 p = yp4[i];
            fvec4 t = yt4[i];
            ACCF4(p, t);
        }
        // scalar tail (n % 4)
        if (tid == 0) {
            for (int i = n4 * 4; i < n; ++i) {
                float pp = yp[i];
                float tt = yt[i];
                ACC(pp, tt);
            }
        }
    }
#undef ACCF4
#undef ACC

    // wave-64 shuffle reduction
    for (int off = 32; off > 0; off >>= 1) {
        ss0 += __shfl_down(ss0, off);
        ss1 += __shfl_down(ss1, off);
        ss2 += __shfl_down(ss2, off);
        ss3 += __shfl_down(ss3, off);
        c0  += __shfl_down(c0,  off);
        c1  += __shfl_down(c1,  off);
        c2  += __shfl_down(c2,  off);
        c3  += __shfl_down(c3,  off);
    }

    __shared__ float        s_ss[4][NBINS];
    __shared__ unsigned int s_cnt[4][NBINS];
    const int lane = tid & 63;
    const int wave = tid >> 6;
    if (lane == 0) {
        s_ss[wave][0] = ss0; s_ss[wave][1] = ss1;
        s_ss[wave][2] = ss2; s_ss[wave][3] = ss3;
        s_cnt[wave][0] = c0; s_cnt[wave][1] = c1;
        s_cnt[wave][2] = c2; s_cnt[wave][3] = c3;
    }
    __syncthreads();

    if (tid == 0) {
        float bs0 = s_ss[0][0] + s_ss[1][0] + s_ss[2][0] + s_ss[3][0];
        float bs1 = s_ss[0][1] + s_ss[1][1] + s_ss[2][1] + s_ss[3][1];
        float bs2 = s_ss[0][2] + s_ss[1][2] + s_ss[2][2] + s_ss[3][2];
        float bs3 = s_ss[0][3] + s_ss[1][3] + s_ss[2][3] + s_ss[3][3];
        unsigned int bc0 = s_cnt[0][0] + s_cnt[1][0] + s_cnt[2][0] + s_cnt[3][0];
        unsigned int bc1 = s_cnt[0][1] + s_cnt[1][1] + s_cnt[2][1] + s_cnt[3][1];
        unsigned int bc2 = s_cnt[0][2] + s_cnt[1][2] + s_cnt[2][2] + s_cnt[3][2];
        unsigned int bc3 = s_cnt[0][3] + s_cnt[1][3] + s_cnt[2][3] + s_cnt[3][3];
        if (use_partials) {
            // plain 16B stores; visibility to the next dispatch is
            // guaranteed by the implicit kernel-end release. NO fences.
            fvec4 v; v.x = bs0; v.y = bs1; v.z = bs2; v.w = bs3;
            uint4 c; c.x = bc0; c.y = bc1; c.z = bc2; c.w = bc3;
            g_bs[b] = v;
            g_bc[b] = c;
        } else {
            const int slot = b & (SLOTS - 1);
            atomicAdd(&g_ss[0 * SLOTS + slot], bs0);
            atomicAdd(&g_ss[1 * SLOTS + slot], bs1);
            atomicAdd(&g_ss[2 * SLOTS + slot], bs2);
            atomicAdd(&g_ss[3 * SLOTS + slot], bs3);
            atomicAdd(&g_cnt[0 * SLOTS + slot], bc0);
            atomicAdd(&g_cnt[1 * SLOTS + slot], bc1);
            atomicAdd(&g_cnt[2 * SLOTS + slot], bc2);
            atomicAdd(&g_cnt[3 * SLOTS + slot], bc3);
        }
    }
}

__device__ __forceinline__ void final_math(
    float s0, float s1, float s2, float s3,
    unsigned int k0, unsigned int k1, unsigned int k2, unsigned int k3,
    float* out)
{
    float ssb[NBINS] = {s0, s1, s2, s3};
    unsigned int cb[NBINS] = {k0, k1, k2, k3};
    float wsum = 0.f;
    float mse[NBINS], w[NBINS];
    bool any = false;
#pragma unroll
    for (int b = 0; b < NBINS; ++b) {
        bool present = (cb[b] > 0);
        any |= present;
        float csafe = present ? (float)cb[b] : 1.0f;
        mse[b] = ssb[b] / csafe;
        w[b] = present ? (1.0f / csafe) : 0.0f;
        wsum += w[b];
    }
    float denom = (wsum > 0.f) ? wsum : 1.0f;
    float wmse = 0.f;
#pragma unroll
    for (int b = 0; b < NBINS; ++b) wmse += (w[b] / denom) * mse[b];
    out[0] = any ? sqrtf(wmse + 1e-8f) : 0.0f;
}

// Finalize for the per-block-partials path: grid-stride over nblocks
// entries (16B each stream, L2-resident), reduce, compute loss.
__global__ __launch_bounds__(256) void qrmse_final_partials(
    const fvec4* __restrict__ g_bs, const uint4* __restrict__ g_bc,
    float* __restrict__ out, int nblocks)
{
    const int tid = threadIdx.x;
    float a0 = 0.f, a1 = 0.f, a2 = 0.f, a3 = 0.f;
    unsigned int k0 = 0, k1 = 0, k2 = 0, k3 = 0;
    for (int i = tid; i < nblocks; i += 256) {
        fvec4 v = g_bs[i];
        uint4 c = g_bc[i];
        a0 += v.x; a1 += v.y; a2 += v.z; a3 += v.w;
        k0 += c.x; k1 += c.y; k2 += c.z; k3 += c.w;
    }
    for (int off = 32; off > 0; off >>= 1) {
        a0 += __shfl_down(a0, off);
        a1 += __shfl_down(a1, off);
        a2 += __shfl_down(a2, off);
        a3 += __shfl_down(a3, off);
        k0 += __shfl_down(k0, off);
        k1 += __shfl_down(k1, off);
        k2 += __shfl_down(k2, off);
        k3 += __shfl_down(k3, off);
    }
    __shared__ float        s_ss[4][NBINS];
    __shared__ unsigned int s_cnt[4][NBINS];
    const int lane = tid & 63;
    const int wave = tid >> 6;
    if (lane == 0) {
        s_ss[wave][0] = a0; s_ss[wave][1] = a1;
        s_ss[wave][2] = a2; s_ss[wave][3] = a3;
        s_cnt[wave][0] = k0; s_cnt[wave][1] = k1;
        s_cnt[wave][2] = k2; s_cnt[wave][3] = k3;
    }
    __syncthreads();
    if (tid == 0) {
        float s0 = s_ss[0][0] + s_ss[1][0] + s_ss[2][0] + s_ss[3][0];
        float s1 = s_ss[0][1] + s_ss[1][1] + s_ss[2][1] + s_ss[3][1];
        float s2 = s_ss[0][2] + s_ss[1][2] + s_ss[2][2] + s_ss[3][2];
        float s3 = s_ss[0][3] + s_ss[1][3] + s_ss[2][3] + s_ss[3][3];
        unsigned int q0 = s_cnt[0][0] + s_cnt[1][0] + s_cnt[2][0] + s_cnt[3][0];
        unsigned int q1 = s_cnt[0][1] + s_cnt[1][1] + s_cnt[2][1] + s_cnt[3][1];
        unsigned int q2 = s_cnt[0][2] + s_cnt[1][2] + s_cnt[2][2] + s_cnt[3][2];
        unsigned int q3 = s_cnt[0][3] + s_cnt[1][3] + s_cnt[2][3] + s_cnt[3][3];
        final_math(s0, s1, s2, s3, q0, q1, q2, q3, out);
    }
}

// Finalize for the atomic-slots fallback path (round-0 version).
__global__ __launch_bounds__(64) void qrmse_final(
    const float* __restrict__ g_ss,
    const unsigned int* __restrict__ g_cnt,
    float* __restrict__ out)
{
    const int lane = threadIdx.x;  // 64 lanes, one per slot
    float ssb[NBINS];
    unsigned int cb[NBINS];
#pragma unroll
    for (int b = 0; b < NBINS; ++b) {
        ssb[b] = g_ss[b * SLOTS + lane];
        cb[b]  = g_cnt[b * SLOTS + lane];
    }
    for (int off = 32; off > 0; off >>= 1) {
#pragma unroll
        for (int b = 0; b < NBINS; ++b) {
            ssb[b] += __shfl_down(ssb[b], off);
            cb[b]  += __shfl_down(cb[b],  off);
        }
    }
    if (lane == 0) {
        final_math(ssb[0], ssb[1], ssb[2], ssb[3],
                   cb[0], cb[1], cb[2], cb[3], out);
    }
}

extern "C" void kernel_launch(void* const* d_in, const int* in_sizes, int n_in,
                              void* d_out, int out_size, void* d_ws, size_t ws_size,
                              hipStream_t stream) {
    const float* yp = (const float*)d_in[0];
    const float* yt = (const float*)d_in[1];
    float* out = (float*)d_out;

    int n  = in_sizes[0];
    int n4 = n / 4;
    int full_blocks = n4 / CHUNK_F4;           // 8640 exactly for this N
    int rem = n4 - full_blocks * CHUNK_F4;
    int grid = full_blocks + ((rem > 0 || (n & 3)) ? 1 : 0);

    size_t need = (size_t)grid * (sizeof(fvec4) + sizeof(uint4));
    if (ws_size >= need) {
        // partials path: no memset dispatch needed (every entry rewritten)
        fvec4* g_bs = (fvec4*)d_ws;
        uint4* g_bc = (uint4*)(g_bs + grid);
        qrmse_bins<<<grid, 256, 0, stream>>>(
            (const fvec4*)yp, (const fvec4*)yt, yp, yt,
            nullptr, nullptr, g_bs, g_bc,
            n4, n, full_blocks, 1);
        qrmse_final_partials<<<1, 256, 0, stream>>>(g_bs, g_bc, out, grid);
    } else {
        // fallback: round-0 atomic-slot path
        float* g_ss = (float*)d_ws;                                   // 4*64 floats
        unsigned int* g_cnt = (unsigned int*)d_ws + NBINS * SLOTS;    // 4*64 uints
        hipMemsetAsync(d_ws, 0, 2 * NBINS * SLOTS * sizeof(float), stream);
        qrmse_bins<<<grid, 256, 0, stream>>>(
            (const fvec4*)yp, (const fvec4*)yt, yp, yt,
            g_ss, g_cnt, nullptr, nullptr,
            n4, n, full_blocks, 0);
        qrmse_final<<<1, 64, 0, stream>>>(g_ss, g_cnt, out);
    }
}

// Round 4
// 267.893 us; speedup vs baseline: 1.1058x; 1.1058x over previous
//
#include <hip/hip_runtime.h>
#include <math.h>

#define NBINS 4
#define SLOTS 64   // atomic-spread slots per bin (fallback path only)

// Round-4 structure: persistent-block streaming reduce.
//  - NT loads (A/B proven: cached loads regressed 72->102us in round 3;
//    NT bypass beats the L2-allocate path for pure streaming).
//  - 2048 persistent blocks (8/CU x 256CU, 32 waves/CU full residency);
//    each loops over chunks with register accumulators. Reduce + store +
//    preamble now run 2048x not 8640x; no block retire/launch churn.
//  - Per-block non-atomic partials -> no memset dispatch (round 2 win).
//  - NO fences anywhere in the producer (round-1 lesson: agent-scope
//    fences emit per-block L2 writeback/inv -> 10x regression). The
//    dispatch boundary is the implicit device-scope release.

#define CHUNK_F4 1024
#define PERSIST_BLOCKS 2048

typedef float fvec4 __attribute__((ext_vector_type(4)));

__device__ __forceinline__ fvec4 ntload(const fvec4* p) {
    return __builtin_nontemporal_load(p);
}

__global__ __launch_bounds__(256) void qrmse_bins(
    const fvec4* __restrict__ yp4, const fvec4* __restrict__ yt4,
    const float* __restrict__ yp, const float* __restrict__ yt,
    float* __restrict__ g_ss, unsigned int* __restrict__ g_cnt,   // slot path
    fvec4* __restrict__ g_bs, uint4* __restrict__ g_bc,           // partials path
    int n4, int n, int full_blocks, int use_partials)
{
    const float B1 = 1.7917594909667969f;   // log1p(5)  in f32
    const float B2 = 3.2580965518951416f;   // log1p(25)
    const float B3 = 3.9318256378173828f;   // log1p(50)
    const float B4 = 4.6151204109191895f;   // log1p(100)

    float ss0 = 0.f, ss1 = 0.f, ss2 = 0.f, ss3 = 0.f;
    unsigned int c0 = 0, c1 = 0, c2 = 0, c3 = 0;

#define ACC(PC, TC)                                          \
    {                                                        \
        float d  = (PC) - (TC);                              \
        float sq = d * d;                                    \
        float tv = (TC);                                     \
        bool b0 = (tv >= 0.f) & (tv < B1);                   \
        bool b1 = (tv >= B1)  & (tv < B2);                   \
        bool b2 = (tv >= B2)  & (tv < B3);                   \
        bool b3 = (tv >= B3)  & (tv < B4);                   \
        ss0 += b0 ? sq : 0.f;  c0 += b0;                     \
        ss1 += b1 ? sq : 0.f;  c1 += b1;                     \
        ss2 += b2 ? sq : 0.f;  c2 += b2;                     \
        ss3 += b3 ? sq : 0.f;  c3 += b3;                     \
    }
#define ACCF4(P, T)                                          \
    { ACC(P.x, T.x); ACC(P.y, T.y); ACC(P.z, T.z); ACC(P.w, T.w); }

    const int tid = threadIdx.x;

    // persistent chunk loop: guard-free hot path, 8 NT 16B loads per iter
    for (int chunk = blockIdx.x; chunk < full_blocks; chunk += gridDim.x) {
        const fvec4* P = yp4 + (size_t)chunk * CHUNK_F4 + tid;
        const fvec4* T = yt4 + (size_t)chunk * CHUNK_F4 + tid;
        fvec4 p0 = ntload(P + 0);
        fvec4 p1 = ntload(P + 256);
        fvec4 p2 = ntload(P + 512);
        fvec4 p3 = ntload(P + 768);
        fvec4 t0 = ntload(T + 0);
        fvec4 t1 = ntload(T + 256);
        fvec4 t2 = ntload(T + 512);
        fvec4 t3 = ntload(T + 768);
        ACCF4(p0, t0); ACCF4(p1, t1); ACCF4(p2, t2); ACCF4(p3, t3);
    }

    // ragged tail (empty when n4 % CHUNK_F4 == 0): block 0 only
    if (blockIdx.x == 0) {
        for (int i = full_blocks * CHUNK_F4 + tid; i < n4; i += 256) {
            fvec4 p = ntload(yp4 + i);
            fvec4 t = ntload(yt4 + i);
            ACCF4(p, t);
        }
        if (tid == 0) {
            for (int i = n4 * 4; i < n; ++i) {
                float pp = yp[i];
                float tt = yt[i];
                ACC(pp, tt);
            }
        }
    }
#undef ACCF4
#undef ACC

    // wave-64 shuffle reduction
    for (int off = 32; off > 0; off >>= 1) {
        ss0 += __shfl_down(ss0, off);
        ss1 += __shfl_down(ss1, off);
        ss2 += __shfl_down(ss2, off);
        ss3 += __shfl_down(ss3, off);
        c0  += __shfl_down(c0,  off);
        c1  += __shfl_down(c1,  off);
        c2  += __shfl_down(c2,  off);
        c3  += __shfl_down(c3,  off);
    }

    __shared__ float        s_ss[4][NBINS];
    __shared__ unsigned int s_cnt[4][NBINS];
    const int lane = tid & 63;
    const int wave = tid >> 6;
    if (lane == 0) {
        s_ss[wave][0] = ss0; s_ss[wave][1] = ss1;
        s_ss[wave][2] = ss2; s_ss[wave][3] = ss3;
        s_cnt[wave][0] = c0; s_cnt[wave][1] = c1;
        s_cnt[wave][2] = c2; s_cnt[wave][3] = c3;
    }
    __syncthreads();

    if (tid == 0) {
        float bs0 = s_ss[0][0] + s_ss[1][0] + s_ss[2][0] + s_ss[3][0];
        float bs1 = s_ss[0][1] + s_ss[1][1] + s_ss[2][1] + s_ss[3][1];
        float bs2 = s_ss[0][2] + s_ss[1][2] + s_ss[2][2] + s_ss[3][2];
        float bs3 = s_ss[0][3] + s_ss[1][3] + s_ss[2][3] + s_ss[3][3];
        unsigned int bc0 = s_cnt[0][0] + s_cnt[1][0] + s_cnt[2][0] + s_cnt[3][0];
        unsigned int bc1 = s_cnt[0][1] + s_cnt[1][1] + s_cnt[2][1] + s_cnt[3][1];
        unsigned int bc2 = s_cnt[0][2] + s_cnt[1][2] + s_cnt[2][2] + s_cnt[3][2];
        unsigned int bc3 = s_cnt[0][3] + s_cnt[1][3] + s_cnt[2][3] + s_cnt[3][3];
        if (use_partials) {
            // plain 16B stores; visible to the next dispatch via the
            // implicit kernel-end release. NO fences.
            fvec4 v; v.x = bs0; v.y = bs1; v.z = bs2; v.w = bs3;
            uint4 c; c.x = bc0; c.y = bc1; c.z = bc2; c.w = bc3;
            g_bs[blockIdx.x] = v;
            g_bc[blockIdx.x] = c;
        } else {
            const int slot = blockIdx.x & (SLOTS - 1);
            atomicAdd(&g_ss[0 * SLOTS + slot], bs0);
            atomicAdd(&g_ss[1 * SLOTS + slot], bs1);
            atomicAdd(&g_ss[2 * SLOTS + slot], bs2);
            atomicAdd(&g_ss[3 * SLOTS + slot], bs3);
            atomicAdd(&g_cnt[0 * SLOTS + slot], bc0);
            atomicAdd(&g_cnt[1 * SLOTS + slot], bc1);
            atomicAdd(&g_cnt[2 * SLOTS + slot], bc2);
            atomicAdd(&g_cnt[3 * SLOTS + slot], bc3);
        }
    }
}

__device__ __forceinline__ void final_math(
    float s0, float s1, float s2, float s3,
    unsigned int k0, unsigned int k1, unsigned int k2, unsigned int k3,
    float* out)
{
    float ssb[NBINS] = {s0, s1, s2, s3};
    unsigned int cb[NBINS] = {k0, k1, k2, k3};
    float wsum = 0.f;
    float mse[NBINS], w[NBINS];
    bool any = false;
#pragma unroll
    for (int b = 0; b < NBINS; ++b) {
        bool present = (cb[b] > 0);
        any |= present;
        float csafe = present ? (float)cb[b] : 1.0f;
        mse[b] = ssb[b] / csafe;
        w[b] = present ? (1.0f / csafe) : 0.0f;
        wsum += w[b];
    }
    float denom = (wsum > 0.f) ? wsum : 1.0f;
    float wmse = 0.f;
#pragma unroll
    for (int b = 0; b < NBINS; ++b) wmse += (w[b] / denom) * mse[b];
    out[0] = any ? sqrtf(wmse + 1e-8f) : 0.0f;
}

// Finalize for the per-block-partials path: grid-stride over nblocks
// entries (L2-resident), reduce, compute loss.
__global__ __launch_bounds__(256) void qrmse_final_partials(
    const fvec4* __restrict__ g_bs, const uint4* __restrict__ g_bc,
    float* __restrict__ out, int nblocks)
{
    const int tid = threadIdx.x;
    float a0 = 0.f, a1 = 0.f, a2 = 0.f, a3 = 0.f;
    unsigned int k0 = 0, k1 = 0, k2 = 0, k3 = 0;
    for (int i = tid; i < nblocks; i += 256) {
        fvec4 v = g_bs[i];
        uint4 c = g_bc[i];
        a0 += v.x; a1 += v.y; a2 += v.z; a3 += v.w;
        k0 += c.x; k1 += c.y; k2 += c.z; k3 += c.w;
    }
    for (int off = 32; off > 0; off >>= 1) {
        a0 += __shfl_down(a0, off);
        a1 += __shfl_down(a1, off);
        a2 += __shfl_down(a2, off);
        a3 += __shfl_down(a3, off);
        k0 += __shfl_down(k0, off);
        k1 += __shfl_down(k1, off);
        k2 += __shfl_down(k2, off);
        k3 += __shfl_down(k3, off);
    }
    __shared__ float        s_ss[4][NBINS];
    __shared__ unsigned int s_cnt[4][NBINS];
    const int lane = tid & 63;
    const int wave = tid >> 6;
    if (lane == 0) {
        s_ss[wave][0] = a0; s_ss[wave][1] = a1;
        s_ss[wave][2] = a2; s_ss[wave][3] = a3;
        s_cnt[wave][0] = k0; s_cnt[wave][1] = k1;
        s_cnt[wave][2] = k2; s_cnt[wave][3] = k3;
    }
    __syncthreads();
    if (tid == 0) {
        float s0 = s_ss[0][0] + s_ss[1][0] + s_ss[2][0] + s_ss[3][0];
        float s1 = s_ss[0][1] + s_ss[1][1] + s_ss[2][1] + s_ss[3][1];
        float s2 = s_ss[0][2] + s_ss[1][2] + s_ss[2][2] + s_ss[3][2];
        float s3 = s_ss[0][3] + s_ss[1][3] + s_ss[2][3] + s_ss[3][3];
        unsigned int q0 = s_cnt[0][0] + s_cnt[1][0] + s_cnt[2][0] + s_cnt[3][0];
        unsigned int q1 = s_cnt[0][1] + s_cnt[1][1] + s_cnt[2][1] + s_cnt[3][1];
        unsigned int q2 = s_cnt[0][2] + s_cnt[1][2] + s_cnt[2][2] + s_cnt[3][2];
        unsigned int q3 = s_cnt[0][3] + s_cnt[1][3] + s_cnt[2][3] + s_cnt[3][3];
        final_math(s0, s1, s2, s3, q0, q1, q2, q3, out);
    }
}

// Finalize for the atomic-slots fallback path.
__global__ __launch_bounds__(64) void qrmse_final(
    const float* __restrict__ g_ss,
    const unsigned int* __restrict__ g_cnt,
    float* __restrict__ out)
{
    const int lane = threadIdx.x;  // 64 lanes, one per slot
    float ssb[NBINS];
    unsigned int cb[NBINS];
#pragma unroll
    for (int b = 0; b < NBINS; ++b) {
        ssb[b] = g_ss[b * SLOTS + lane];
        cb[b]  = g_cnt[b * SLOTS + lane];
    }
    for (int off = 32; off > 0; off >>= 1) {
#pragma unroll
        for (int b = 0; b < NBINS; ++b) {
            ssb[b] += __shfl_down(ssb[b], off);
            cb[b]  += __shfl_down(cb[b],  off);
        }
    }
    if (lane == 0) {
        final_math(ssb[0], ssb[1], ssb[2], ssb[3],
                   cb[0], cb[1], cb[2], cb[3], out);
    }
}

extern "C" void kernel_launch(void* const* d_in, const int* in_sizes, int n_in,
                              void* d_out, int out_size, void* d_ws, size_t ws_size,
                              hipStream_t stream) {
    const float* yp = (const float*)d_in[0];
    const float* yt = (const float*)d_in[1];
    float* out = (float*)d_out;

    int n  = in_sizes[0];
    int n4 = n / 4;
    int full_blocks = n4 / CHUNK_F4;           // 8640 exactly for this N

    int grid = full_blocks < PERSIST_BLOCKS
                 ? (full_blocks > 0 ? full_blocks : 1)
                 : PERSIST_BLOCKS;

    size_t need = (size_t)grid * (sizeof(fvec4) + sizeof(uint4));
    if (ws_size >= need) {
        // partials path: no memset dispatch (every entry rewritten)
        fvec4* g_bs = (fvec4*)d_ws;
        uint4* g_bc = (uint4*)(g_bs + grid);
        qrmse_bins<<<grid, 256, 0, stream>>>(
            (const fvec4*)yp, (const fvec4*)yt, yp, yt,
            nullptr, nullptr, g_bs, g_bc,
            n4, n, full_blocks, 1);
        qrmse_final_partials<<<1, 256, 0, stream>>>(g_bs, g_bc, out, grid);
    } else {
        // fallback: memset + atomic-slot path
        float* g_ss = (float*)d_ws;                                   // 4*64 floats
        unsigned int* g_cnt = (unsigned int*)d_ws + NBINS * SLOTS;    // 4*64 uints
        hipMemsetAsync(d_ws, 0, 2 * NBINS * SLOTS * sizeof(float), stream);
        qrmse_bins<<<grid, 256, 0, stream>>>(
            (const fvec4*)yp, (const fvec4*)yt, yp, yt,
            g_ss, g_cnt, nullptr, nullptr,
            n4, n, full_blocks, 0);
        qrmse_final<<<1, 64, 0, stream>>>(g_ss, g_cnt, out);
    }
}

// Round 5
// 266.246 us; speedup vs baseline: 1.1127x; 1.0062x over previous
//
#include <hip/hip_runtime.h>
#include <math.h>

#define NBINS 4
#define SLOTS 64   // atomic-spread slots per bin (fallback path only)

// Round-5 structure: persistent blocks + 2-chunk unrolled NT streaming.
//  - NT loads (A/B proven: cached 102us vs NT ~70us).
//  - FETCH_SIZE on gfx950 under-counts reads 2x (identical 141.6MB across
//    three very different kernels = exactly half of 283MB). True read BW:
//    NT 4.04 TB/s vs 6.3 achievable -> this round deepens the issue stream:
//    16 back-to-back NT loads per thread per iteration (2 chunks).
//  - Per-block non-atomic partials -> no memset dispatch.
//  - NO fences in producer (round-1: agent fences -> L2 wb/inv storm, 10x).

#define CHUNK_F4 1024
#define PERSIST_BLOCKS 2048

typedef float fvec4 __attribute__((ext_vector_type(4)));

__device__ __forceinline__ fvec4 ntload(const fvec4* p) {
    return __builtin_nontemporal_load(p);
}

__global__ __launch_bounds__(256) void qrmse_bins(
    const fvec4* __restrict__ yp4, const fvec4* __restrict__ yt4,
    const float* __restrict__ yp, const float* __restrict__ yt,
    float* __restrict__ g_ss, unsigned int* __restrict__ g_cnt,   // slot path
    fvec4* __restrict__ g_bs, uint4* __restrict__ g_bc,           // partials path
    int n4, int n, int full_blocks, int use_partials)
{
    const float B1 = 1.7917594909667969f;   // log1p(5)  in f32
    const float B2 = 3.2580965518951416f;   // log1p(25)
    const float B3 = 3.9318256378173828f;   // log1p(50)
    const float B4 = 4.6151204109191895f;   // log1p(100)

    float ss0 = 0.f, ss1 = 0.f, ss2 = 0.f, ss3 = 0.f;
    unsigned int c0 = 0, c1 = 0, c2 = 0, c3 = 0;

#define ACC(PC, TC)                                          \
    {                                                        \
        float d  = (PC) - (TC);                              \
        float sq = d * d;                                    \
        float tv = (TC);                                     \
        bool b0 = (tv >= 0.f) & (tv < B1);                   \
        bool b1 = (tv >= B1)  & (tv < B2);                   \
        bool b2 = (tv >= B2)  & (tv < B3);                   \
        bool b3 = (tv >= B3)  & (tv < B4);                   \
        ss0 += b0 ? sq : 0.f;  c0 += b0;                     \
        ss1 += b1 ? sq : 0.f;  c1 += b1;                     \
        ss2 += b2 ? sq : 0.f;  c2 += b2;                     \
        ss3 += b3 ? sq : 0.f;  c3 += b3;                     \
    }
#define ACCF4(P, T)                                          \
    { ACC(P.x, T.x); ACC(P.y, T.y); ACC(P.z, T.z); ACC(P.w, T.w); }

    const int tid = threadIdx.x;

    // persistent loop over PAIRS of chunks: 16 independent NT 16B loads
    // issued back-to-back before any accumulation.
    const int pairs = full_blocks >> 1;
    for (int u = blockIdx.x; u < pairs; u += gridDim.x) {
        const fvec4* P = yp4 + (size_t)u * (2 * CHUNK_F4) + tid;
        const fvec4* T = yt4 + (size_t)u * (2 * CHUNK_F4) + tid;
        fvec4 p0 = ntload(P + 0);
        fvec4 p1 = ntload(P + 256);
        fvec4 p2 = ntload(P + 512);
        fvec4 p3 = ntload(P + 768);
        fvec4 p4 = ntload(P + 1024);
        fvec4 p5 = ntload(P + 1280);
        fvec4 p6 = ntload(P + 1536);
        fvec4 p7 = ntload(P + 1792);
        fvec4 t0 = ntload(T + 0);
        fvec4 t1 = ntload(T + 256);
        fvec4 t2 = ntload(T + 512);
        fvec4 t3 = ntload(T + 768);
        fvec4 t4 = ntload(T + 1024);
        fvec4 t5 = ntload(T + 1280);
        fvec4 t6 = ntload(T + 1536);
        fvec4 t7 = ntload(T + 1792);
        ACCF4(p0, t0); ACCF4(p1, t1); ACCF4(p2, t2); ACCF4(p3, t3);
        ACCF4(p4, t4); ACCF4(p5, t5); ACCF4(p6, t6); ACCF4(p7, t7);
    }

    // odd leftover chunk (dead for 8640 chunks): last block handles it
    if ((full_blocks & 1) && blockIdx.x == gridDim.x - 1) {
        const int chunk = full_blocks - 1;
        const fvec4* P = yp4 + (size_t)chunk * CHUNK_F4 + tid;
        const fvec4* T = yt4 + (size_t)chunk * CHUNK_F4 + tid;
        fvec4 p0 = ntload(P + 0);
        fvec4 p1 = ntload(P + 256);
        fvec4 p2 = ntload(P + 512);
        fvec4 p3 = ntload(P + 768);
        fvec4 t0 = ntload(T + 0);
        fvec4 t1 = ntload(T + 256);
        fvec4 t2 = ntload(T + 512);
        fvec4 t3 = ntload(T + 768);
        ACCF4(p0, t0); ACCF4(p1, t1); ACCF4(p2, t2); ACCF4(p3, t3);
    }

    // ragged tail (empty when n4 % CHUNK_F4 == 0): block 0 only
    if (blockIdx.x == 0) {
        for (int i = full_blocks * CHUNK_F4 + tid; i < n4; i += 256) {
            fvec4 p = ntload(yp4 + i);
            fvec4 t = ntload(yt4 + i);
            ACCF4(p, t);
        }
        if (tid == 0) {
            for (int i = n4 * 4; i < n; ++i) {
                float pp = yp[i];
                float tt = yt[i];
                ACC(pp, tt);
            }
        }
    }
#undef ACCF4
#undef ACC

    // wave-64 shuffle reduction
    for (int off = 32; off > 0; off >>= 1) {
        ss0 += __shfl_down(ss0, off);
        ss1 += __shfl_down(ss1, off);
        ss2 += __shfl_down(ss2, off);
        ss3 += __shfl_down(ss3, off);
        c0  += __shfl_down(c0,  off);
        c1  += __shfl_down(c1,  off);
        c2  += __shfl_down(c2,  off);
        c3  += __shfl_down(c3,  off);
    }

    __shared__ float        s_ss[4][NBINS];
    __shared__ unsigned int s_cnt[4][NBINS];
    const int lane = tid & 63;
    const int wave = tid >> 6;
    if (lane == 0) {
        s_ss[wave][0] = ss0; s_ss[wave][1] = ss1;
        s_ss[wave][2] = ss2; s_ss[wave][3] = ss3;
        s_cnt[wave][0] = c0; s_cnt[wave][1] = c1;
        s_cnt[wave][2] = c2; s_cnt[wave][3] = c3;
    }
    __syncthreads();

    if (tid == 0) {
        float bs0 = s_ss[0][0] + s_ss[1][0] + s_ss[2][0] + s_ss[3][0];
        float bs1 = s_ss[0][1] + s_ss[1][1] + s_ss[2][1] + s_ss[3][1];
        float bs2 = s_ss[0][2] + s_ss[1][2] + s_ss[2][2] + s_ss[3][2];
        float bs3 = s_ss[0][3] + s_ss[1][3] + s_ss[2][3] + s_ss[3][3];
        unsigned int bc0 = s_cnt[0][0] + s_cnt[1][0] + s_cnt[2][0] + s_cnt[3][0];
        unsigned int bc1 = s_cnt[0][1] + s_cnt[1][1] + s_cnt[2][1] + s_cnt[3][1];
        unsigned int bc2 = s_cnt[0][2] + s_cnt[1][2] + s_cnt[2][2] + s_cnt[3][2];
        unsigned int bc3 = s_cnt[0][3] + s_cnt[1][3] + s_cnt[2][3] + s_cnt[3][3];
        if (use_partials) {
            // plain 16B stores; visible to the next dispatch via the
            // implicit kernel-end release. NO fences.
            fvec4 v; v.x = bs0; v.y = bs1; v.z = bs2; v.w = bs3;
            uint4 c; c.x = bc0; c.y = bc1; c.z = bc2; c.w = bc3;
            g_bs[blockIdx.x] = v;
            g_bc[blockIdx.x] = c;
        } else {
            const int slot = blockIdx.x & (SLOTS - 1);
            atomicAdd(&g_ss[0 * SLOTS + slot], bs0);
            atomicAdd(&g_ss[1 * SLOTS + slot], bs1);
            atomicAdd(&g_ss[2 * SLOTS + slot], bs2);
            atomicAdd(&g_ss[3 * SLOTS + slot], bs3);
            atomicAdd(&g_cnt[0 * SLOTS + slot], bc0);
            atomicAdd(&g_cnt[1 * SLOTS + slot], bc1);
            atomicAdd(&g_cnt[2 * SLOTS + slot], bc2);
            atomicAdd(&g_cnt[3 * SLOTS + slot], bc3);
        }
    }
}

__device__ __forceinline__ void final_math(
    float s0, float s1, float s2, float s3,
    unsigned int k0, unsigned int k1, unsigned int k2, unsigned int k3,
    float* out)
{
    float ssb[NBINS] = {s0, s1, s2, s3};
    unsigned int cb[NBINS] = {k0, k1, k2, k3};
    float wsum = 0.f;
    float mse[NBINS], w[NBINS];
    bool any = false;
#pragma unroll
    for (int b = 0; b < NBINS; ++b) {
        bool present = (cb[b] > 0);
        any |= present;
        float csafe = present ? (float)cb[b] : 1.0f;
        mse[b] = ssb[b] / csafe;
        w[b] = present ? (1.0f / csafe) : 0.0f;
        wsum += w[b];
    }
    float denom = (wsum > 0.f) ? wsum : 1.0f;
    float wmse = 0.f;
#pragma unroll
    for (int b = 0; b < NBINS; ++b) wmse += (w[b] / denom) * mse[b];
    out[0] = any ? sqrtf(wmse + 1e-8f) : 0.0f;
}

// Finalize for the per-block-partials path: grid-stride over nblocks
// entries (L2-resident), reduce, compute loss.
__global__ __launch_bounds__(256) void qrmse_final_partials(
    const fvec4* __restrict__ g_bs, const uint4* __restrict__ g_bc,
    float* __restrict__ out, int nblocks)
{
    const int tid = threadIdx.x;
    float a0 = 0.f, a1 = 0.f, a2 = 0.f, a3 = 0.f;
    unsigned int k0 = 0, k1 = 0, k2 = 0, k3 = 0;
    for (int i = tid; i < nblocks; i += 256) {
        fvec4 v = g_bs[i];
        uint4 c = g_bc[i];
        a0 += v.x; a1 += v.y; a2 += v.z; a3 += v.w;
        k0 += c.x; k1 += c.y; k2 += c.z; k3 += c.w;
    }
    for (int off = 32; off > 0; off >>= 1) {
        a0 += __shfl_down(a0, off);
        a1 += __shfl_down(a1, off);
        a2 += __shfl_down(a2, off);
        a3 += __shfl_down(a3, off);
        k0 += __shfl_down(k0, off);
        k1 += __shfl_down(k1, off);
        k2 += __shfl_down(k2, off);
        k3 += __shfl_down(k3, off);
    }
    __shared__ float        s_ss[4][NBINS];
    __shared__ unsigned int s_cnt[4][NBINS];
    const int lane = tid & 63;
    const int wave = tid >> 6;
    if (lane == 0) {
        s_ss[wave][0] = a0; s_ss[wave][1] = a1;
        s_ss[wave][2] = a2; s_ss[wave][3] = a3;
        s_cnt[wave][0] = k0; s_cnt[wave][1] = k1;
        s_cnt[wave][2] = k2; s_cnt[wave][3] = k3;
    }
    __syncthreads();
    if (tid == 0) {
        float s0 = s_ss[0][0] + s_ss[1][0] + s_ss[2][0] + s_ss[3][0];
        float s1 = s_ss[0][1] + s_ss[1][1] + s_ss[2][1] + s_ss[3][1];
        float s2 = s_ss[0][2] + s_ss[1][2] + s_ss[2][2] + s_ss[3][2];
        float s3 = s_ss[0][3] + s_ss[1][3] + s_ss[2][3] + s_ss[3][3];
        unsigned int q0 = s_cnt[0][0] + s_cnt[1][0] + s_cnt[2][0] + s_cnt[3][0];
        unsigned int q1 = s_cnt[0][1] + s_cnt[1][1] + s_cnt[2][1] + s_cnt[3][1];
        unsigned int q2 = s_cnt[0][2] + s_cnt[1][2] + s_cnt[2][2] + s_cnt[3][2];
        unsigned int q3 = s_cnt[0][3] + s_cnt[1][3] + s_cnt[2][3] + s_cnt[3][3];
        final_math(s0, s1, s2, s3, q0, q1, q2, q3, out);
    }
}

// Finalize for the atomic-slots fallback path.
__global__ __launch_bounds__(64) void qrmse_final(
    const float* __restrict__ g_ss,
    const unsigned int* __restrict__ g_cnt,
    float* __restrict__ out)
{
    const int lane = threadIdx.x;  // 64 lanes, one per slot
    float ssb[NBINS];
    unsigned int cb[NBINS];
#pragma unroll
    for (int b = 0; b < NBINS; ++b) {
        ssb[b] = g_ss[b * SLOTS + lane];
        cb[b]  = g_cnt[b * SLOTS + lane];
    }
    for (int off = 32; off > 0; off >>= 1) {
#pragma unroll
        for (int b = 0; b < NBINS; ++b) {
            ssb[b] += __shfl_down(ssb[b], off);
            cb[b]  += __shfl_down(cb[b],  off);
        }
    }
    if (lane == 0) {
        final_math(ssb[0], ssb[1], ssb[2], ssb[3],
                   cb[0], cb[1], cb[2], cb[3], out);
    }
}

extern "C" void kernel_launch(void* const* d_in, const int* in_sizes, int n_in,
                              void* d_out, int out_size, void* d_ws, size_t ws_size,
                              hipStream_t stream) {
    const float* yp = (const float*)d_in[0];
    const float* yt = (const float*)d_in[1];
    float* out = (float*)d_out;

    int n  = in_sizes[0];
    int n4 = n / 4;
    int full_blocks = n4 / CHUNK_F4;           // 8640 exactly for this N
    int pairs = full_blocks >> 1;

    int grid = pairs < PERSIST_BLOCKS
                 ? (pairs > 0 ? pairs : 1)
                 : PERSIST_BLOCKS;

    size_t need = (size_t)grid * (sizeof(fvec4) + sizeof(uint4));
    if (ws_size >= need) {
        // partials path: no memset dispatch (every entry rewritten)
        fvec4* g_bs = (fvec4*)d_ws;
        uint4* g_bc = (uint4*)(g_bs + grid);
        qrmse_bins<<<grid, 256, 0, stream>>>(
            (const fvec4*)yp, (const fvec4*)yt, yp, yt,
            nullptr, nullptr, g_bs, g_bc,
            n4, n, full_blocks, 1);
        qrmse_final_partials<<<1, 256, 0, stream>>>(g_bs, g_bc, out, grid);
    } else {
        // fallback: memset + atomic-slot path
        float* g_ss = (float*)d_ws;                                   // 4*64 floats
        unsigned int* g_cnt = (unsigned int*)d_ws + NBINS * SLOTS;    // 4*64 uints
        hipMemsetAsync(d_ws, 0, 2 * NBINS * SLOTS * sizeof(float), stream);
        qrmse_bins<<<grid, 256, 0, stream>>>(
            (const fvec4*)yp, (const fvec4*)yt, yp, yt,
            g_ss, g_cnt, nullptr, nullptr,
            n4, n, full_blocks, 0);
        qrmse_final<<<1, 64, 0, stream>>>(g_ss, g_cnt, out);
    }
}